// Round 1
// baseline (75.319 us; speedup 1.0000x reference)
//
#include <hip/hip_runtime.h>
#include <stdint.h>

#define BB 4
#define LL 4096
#define DD 64

typedef __attribute__((ext_vector_type(8))) short bf16x8;
typedef __attribute__((ext_vector_type(4))) float f32x4;

static __device__ __forceinline__ unsigned short f2bf(float x) {
    // round-to-nearest-even f32 -> bf16
    unsigned int u = __builtin_bit_cast(unsigned int, x);
    u += 0x7fffu + ((u >> 16) & 1u);
    return (unsigned short)(u >> 16);
}

// ---------------------------------------------------------------------------
// Kernel 1: convert q,k (f32) -> bf16 in ws. k-blocks also emit deterministic
// per-block column partial sums (32 rows x 64 cols per block).
// grid = 1024 (512 q-blocks, 512 k-blocks), 256 threads, 8 elems/thread.
// ---------------------------------------------------------------------------
__global__ __launch_bounds__(256) void convert_kernel(
    const float* __restrict__ q, const float* __restrict__ k,
    unsigned short* __restrict__ qbf, unsigned short* __restrict__ kbf,
    float* __restrict__ part)
{
    const int NBQ = (BB * LL * DD) / 2048;   // 512
    int bid = blockIdx.x;
    bool is_k = bid >= NBQ;
    const float* src = is_k ? k : q;
    unsigned short* dst = is_k ? kbf : qbf;
    int cb = is_k ? (bid - NBQ) : bid;
    int tid = threadIdx.x;

    size_t idx0 = (size_t)cb * 2048 + (size_t)tid * 8;
    float4 f0 = *(const float4*)(src + idx0);
    float4 f1 = *(const float4*)(src + idx0 + 4);
    float f[8] = {f0.x, f0.y, f0.z, f0.w, f1.x, f1.y, f1.z, f1.w};

    unsigned short u[8];
    #pragma unroll
    for (int e = 0; e < 8; e++) u[e] = f2bf(f[e]);
    uint4 pk;
    pk.x = (unsigned)u[0] | ((unsigned)u[1] << 16);
    pk.y = (unsigned)u[2] | ((unsigned)u[3] << 16);
    pk.z = (unsigned)u[4] | ((unsigned)u[5] << 16);
    pk.w = (unsigned)u[6] | ((unsigned)u[7] << 16);
    *(uint4*)(dst + idx0) = pk;

    if (is_k) {
        // block covers rows [cb*32, cb*32+32) of the flattened [B*L][64] k.
        // thread tid holds row (tid>>3), cols (tid&7)*8 .. +7
        __shared__ float red[256][8];
        #pragma unroll
        for (int e = 0; e < 8; e++) red[tid][e] = f[e];
        __syncthreads();
        if (tid < 64) {
            // column c = tid: group g = c>>3, elem e = c&7
            int g = tid >> 3, e = tid & 7;
            float s = 0.f;
            #pragma unroll
            for (int r = 0; r < 32; r++) s += red[r * 8 + g][e];
            part[(size_t)cb * 64 + tid] = s;   // cb = b*128 + chunk (deterministic)
        }
    }
}

// ---------------------------------------------------------------------------
// Kernel 2: output[b,i,r] = sum_t q[b,i,t]*coef[b,t]*v[b,t,r]
// coef[b,t] = 0.0625*(vec[0,t]+vec[1,t]) * ksum[b,t];  ksum from partials.
// grid = B * (L/32) = 512 blocks, 256 threads. Each block: 32 rows of output.
// ---------------------------------------------------------------------------
__global__ __launch_bounds__(256) void out_kernel(
    const float* __restrict__ q, const float* __restrict__ v,
    const float* __restrict__ vec, const float* __restrict__ part,
    float* __restrict__ out)
{
    __shared__ float csh[64];
    __shared__ float Vl[64][65];
    __shared__ float qs[32][65];

    int bid = blockIdx.x;
    int b   = bid >> 7;            // 128 blocks per batch
    int i0  = (bid & 127) << 5;    // row base
    int tid = threadIdx.x;

    if (tid < 64) {
        const float* pp = part + (size_t)b * 128 * 64 + tid;
        float s = 0.f;
        #pragma unroll 8
        for (int c = 0; c < 128; c++) s += pp[c * 64];
        csh[tid] = 0.0625f * (vec[tid] + vec[64 + tid]) * s;  // 0.5/TEMPERATURE
    }
    // load V tile: v[b, 0:64, 0:64]
    {
        const float* vb = v + (size_t)b * LL * DD;
        #pragma unroll
        for (int it = 0; it < 4; it++) {
            int idx4 = it * 256 + tid;          // float4 index, 1024 total
            int t  = idx4 >> 4;
            int r4 = (idx4 & 15) << 2;
            float4 w = *(const float4*)(vb + (size_t)idx4 * 4);
            Vl[t][r4 + 0] = w.x; Vl[t][r4 + 1] = w.y;
            Vl[t][r4 + 2] = w.z; Vl[t][r4 + 3] = w.w;
        }
    }
    __syncthreads();
    // load 32 q rows, pre-scaled by coef
    {
        const float* qb = q + (size_t)b * LL * DD;
        int row = tid >> 3;
        int t0  = (tid & 7) << 3;
        const float* src = qb + (size_t)(i0 + row) * DD + t0;
        float4 a0 = *(const float4*)(src);
        float4 a1 = *(const float4*)(src + 4);
        float fa[8] = {a0.x,a0.y,a0.z,a0.w,a1.x,a1.y,a1.z,a1.w};
        #pragma unroll
        for (int e = 0; e < 8; e++) qs[row][t0 + e] = fa[e] * csh[t0 + e];
    }
    __syncthreads();

    int ii = tid >> 3;
    int g  = tid & 7;
    float acc[8] = {0,0,0,0,0,0,0,0};
    #pragma unroll 8
    for (int t = 0; t < 64; t++) {
        float qv = qs[ii][t];
        #pragma unroll
        for (int j = 0; j < 8; j++) acc[j] += qv * Vl[t][g * 8 + j];
    }
    float* op = out + (size_t)b * LL * DD + (size_t)(i0 + ii) * DD + g * 8;
    float4 s0 = {acc[0], acc[1], acc[2], acc[3]};
    float4 s1 = {acc[4], acc[5], acc[6], acc[7]};
    *(float4*)(op)     = s0;
    *(float4*)(op + 4) = s1;
}

// ---------------------------------------------------------------------------
// Kernel 3: attn[b,i,j] = sum_d q[b,i,d]*k[b,j,d]  (bf16 MFMA, f32 out)
// 128x128 tile per block, 4 waves, each wave a 64x64 sub-tile.
// K=64 -> 2 k-steps of mfma_f32_16x16x32_bf16. Store-bound by design.
// grid = 4 * 32 * 32 = 4096 blocks.
// ---------------------------------------------------------------------------
__global__ __launch_bounds__(256) void attn_kernel(
    const unsigned short* __restrict__ qbf,
    const unsigned short* __restrict__ kbf,
    float* __restrict__ attn)
{
    int bid = blockIdx.x;
    // XCD-aware swizzle: 4096 % 8 == 0, contiguous 512-block chunk per XCD
    int swz = (bid & 7) * 512 + (bid >> 3);
    int b   = swz >> 10;
    int rem = swz & 1023;
    int ti  = rem >> 5;
    int tj  = rem & 31;

    int tid  = threadIdx.x;
    int wid  = tid >> 6;
    int lane = tid & 63;
    int wm = wid >> 1, wn = wid & 1;
    int row0 = ti * 128 + wm * 64;
    int col0 = tj * 128 + wn * 64;

    const unsigned short* qb = qbf + (size_t)b * LL * DD;
    const unsigned short* kb = kbf + (size_t)b * LL * DD;

    int lr = lane & 15;          // fragment row/col within 16
    int lk = (lane >> 4) * 8;    // k-octet base within 32

    f32x4 acc[4][4];
    #pragma unroll
    for (int m = 0; m < 4; m++)
        #pragma unroll
        for (int n = 0; n < 4; n++)
            acc[m][n] = (f32x4){0.f, 0.f, 0.f, 0.f};

    #pragma unroll
    for (int kk = 0; kk < 2; kk++) {
        int k0 = kk * 32 + lk;
        bf16x8 a[4], bf[4];
        #pragma unroll
        for (int m = 0; m < 4; m++)
            a[m] = *(const bf16x8*)(qb + (size_t)(row0 + m * 16 + lr) * DD + k0);
        #pragma unroll
        for (int n = 0; n < 4; n++)
            bf[n] = *(const bf16x8*)(kb + (size_t)(col0 + n * 16 + lr) * DD + k0);
        #pragma unroll
        for (int m = 0; m < 4; m++)
            #pragma unroll
            for (int n = 0; n < 4; n++)
                acc[m][n] = __builtin_amdgcn_mfma_f32_16x16x32_bf16(
                    a[m], bf[n], acc[m][n], 0, 0, 0);
    }

    float* ab = attn + (size_t)b * LL * LL;
    int rbase = (lane >> 4) * 4;
    #pragma unroll
    for (int m = 0; m < 4; m++) {
        #pragma unroll
        for (int reg = 0; reg < 4; reg++) {
            size_t roff = (size_t)(row0 + m * 16 + rbase + reg) * LL + col0 + lr;
            #pragma unroll
            for (int n = 0; n < 4; n++)
                ab[roff + n * 16] = acc[m][n][reg];
        }
    }
}

extern "C" void kernel_launch(void* const* d_in, const int* in_sizes, int n_in,
                              void* d_out, int out_size, void* d_ws, size_t ws_size,
                              hipStream_t stream) {
    const float* q   = (const float*)d_in[0];
    const float* k   = (const float*)d_in[1];
    const float* v   = (const float*)d_in[2];
    const float* vec = (const float*)d_in[3];

    float* out  = (float*)d_out;                          // [4,4096,64]
    float* attn = out + (size_t)BB * LL * DD;             // [4,4096,4096]

    unsigned short* qbf = (unsigned short*)d_ws;          // 2 MB
    unsigned short* kbf = qbf + (size_t)BB * LL * DD;     // 2 MB
    float* part = (float*)(kbf + (size_t)BB * LL * DD);   // 512*64 f32 = 128 KB

    convert_kernel<<<1024, 256, 0, stream>>>(q, k, qbf, kbf, part);
    out_kernel<<<512, 256, 0, stream>>>(q, v, vec, part, out);
    attn_kernel<<<4096, 256, 0, stream>>>(qbf, kbf, attn);
}